// Round 1
// baseline (791.747 us; speedup 1.0000x reference)
//
#include <hip/hip_runtime.h>

#define DEVINL __device__ __forceinline__

// ---------------------------------------------------------------------------
// Compile-time structure: allowed (l1,l2,l3) triples, slot table, CG sparsity
// pattern from real-SH m-selection rules. CG *values* are computed on device.
// ---------------------------------------------------------------------------
constexpr int LMAX = 4;

struct Triples {
  int n; int nslot;
  int l1[80], l2[80], l3[80], slot0[80];
};
constexpr Triples make_triples() {
  Triples T{}; T.n = 0; int s = 0;
  for (int a = 0; a <= LMAX; ++a)
    for (int b = 0; b <= LMAX; ++b)
      for (int c = 0; c <= LMAX; ++c) {
        int lo = a > b ? a - b : b - a;
        if (c < lo || c > a + b) continue;
        T.l1[T.n] = a; T.l2[T.n] = b; T.l3[T.n] = c; T.slot0[T.n] = s;
        s += 2 * c + 1; ++T.n;
      }
  T.nslot = s; return T;
}
constexpr Triples TRI = make_triples();
static_assert(TRI.n == 65, "triples");
static_assert(TRI.nslot == 375, "slots");

constexpr int NSLOT  = 375;
constexpr int CHUNK  = 48;
constexpr int NCHUNK = 8;                    // 8*48 = 384 >= 375
constexpr int NSLOT4 = NCHUNK * CHUNK / 4;   // 96 float4 groups

constexpr int cabs_(int x) { return x < 0 ? -x : x; }

constexpr int count_pat() {
  int cnt = 0;
  for (int t = 0; t < TRI.n; ++t) {
    int l1 = TRI.l1[t], l2 = TRI.l2[t], l3 = TRI.l3[t];
    for (int mc = -l3; mc <= l3; ++mc)
      for (int a = 0; a < 2 * l1 + 1; ++a)
        for (int b = 0; b < 2 * l2 + 1; ++b) {
          int Ma = a - l1, Mb = b - l2;
          int su = cabs_(Ma) + cabs_(Mb), di = cabs_(cabs_(Ma) - cabs_(Mb));
          if (cabs_(mc) == su || cabs_(mc) == di) ++cnt;
        }
  }
  return cnt;
}
constexpr int NNZ = count_pat();
static_assert(NNZ <= 12000, "pattern size sanity");

template <int N> struct PatT { short i[N]; short j[N]; short slot[N]; };
constexpr PatT<NNZ> make_pat() {
  PatT<NNZ> P{}; int cnt = 0;
  for (int t = 0; t < TRI.n; ++t) {
    int l1 = TRI.l1[t], l2 = TRI.l2[t], l3 = TRI.l3[t];
    for (int mc = -l3; mc <= l3; ++mc) {
      int slot = TRI.slot0[t] + (mc + l3);
      for (int a = 0; a < 2 * l1 + 1; ++a)
        for (int b = 0; b < 2 * l2 + 1; ++b) {
          int Ma = a - l1, Mb = b - l2;
          int su = cabs_(Ma) + cabs_(Mb), di = cabs_(cabs_(Ma) - cabs_(Mb));
          if (cabs_(mc) == su || cabs_(mc) == di) {
            P.i[cnt] = (short)(l1 * l1 + a);
            P.j[cnt] = (short)(l2 * l2 + b);
            P.slot[cnt] = (short)slot;
            ++cnt;
          }
        }
    }
  }
  return P;
}
constexpr PatT<NNZ> PAT = make_pat();

struct ChunkB { int b[NCHUNK + 1]; };
constexpr ChunkB make_chunks() {
  ChunkB C{};
  for (int c = 0; c <= NCHUNK; ++c) {
    int t = 0;
    while (t < NNZ && PAT.slot[t] < c * CHUNK) ++t;
    C.b[c] = t;
  }
  return C;
}
constexpr ChunkB CB = make_chunks();

struct SlotTab { signed char k[NCHUNK * CHUNK]; signed char tri[NCHUNK * CHUNK]; };
constexpr SlotTab make_slots() {
  SlotTab S{};
  for (int s = 0; s < NCHUNK * CHUNK; ++s) { S.k[s] = -1; S.tri[s] = 0; }
  for (int t = 0; t < TRI.n; ++t) {
    int l3 = TRI.l3[t];
    for (int m = 0; m < 2 * l3 + 1; ++m) {
      int s = TRI.slot0[t] + m;
      S.k[s] = (signed char)(l3 * l3 + m);
      S.tri[s] = (signed char)t;
    }
  }
  return S;
}
constexpr SlotTab SLOT = make_slots();

// ---------------------------------------------------------------------------
// Device computation of real-basis CG values (double), matching the reference
// ---------------------------------------------------------------------------
DEVINL double dfact(int n) {
  const double F[14] = {1., 1., 2., 6., 24., 120., 720., 5040., 40320.,
                        362880., 3628800., 39916800., 479001600., 6227020800.};
  return F[n];
}

DEVINL double cg_complex_d(int l1, int m1, int l2, int m2, int l3, int m3) {
  if (m1 + m2 != m3) return 0.0;
  double pref = sqrt((2.0 * l3 + 1.0) * dfact(l1 + l2 - l3) * dfact(l1 - l2 + l3) *
                     dfact(-l1 + l2 + l3) / dfact(l1 + l2 + l3 + 1));
  pref *= sqrt(dfact(l1 + m1) * dfact(l1 - m1) * dfact(l2 + m2) * dfact(l2 - m2) *
               dfact(l3 + m3) * dfact(l3 - m3));
  double s = 0.0;
  for (int k = 0; k <= l1 + l2 - l3; ++k) {
    int d3 = l1 - m1 - k, d4 = l2 + m2 - k, d5 = l3 - l2 + m1 + k, d6 = l3 - l1 - m2 + k;
    if (d3 < 0 || d4 < 0 || d5 < 0 || d6 < 0) continue;
    double den = dfact(k) * dfact(l1 + l2 - l3 - k) * dfact(d3) * dfact(d4) *
                 dfact(d5) * dfact(d6);
    s += ((k & 1) ? -1.0 : 1.0) / den;
  }
  return pref * s;
}

struct C2 { double re, im; };
DEVINL C2 cmul(C2 x, C2 y) { return {x.re * y.re - x.im * y.im, x.re * y.im + x.im * y.re}; }

struct URow { int n; int m[2]; double re[2], im[2]; };
DEVINL URow u_row(int l, int a) {
  URow u{}; int ma = a - l;
  const double RS2 = 0.70710678118654752440;
  if (ma == 0) { u.n = 1; u.m[0] = 0; u.re[0] = 1.0; u.im[0] = 0.0; }
  else if (ma > 0) {
    u.n = 2;
    u.m[0] = ma;  u.re[0] = ((ma & 1) ? -RS2 : RS2); u.im[0] = 0.0;
    u.m[1] = -ma; u.re[1] = RS2;                     u.im[1] = 0.0;
  } else {
    int mm = -ma; u.n = 2;
    u.m[0] = -mm; u.re[0] = 0.0; u.im[0] = RS2;
    u.m[1] =  mm; u.re[1] = 0.0; u.im[1] = ((mm & 1) ? RS2 : -RS2);
  }
  return u;
}

__global__ void kcg(float* __restrict__ cgv) {
  int t = blockIdx.x * 256 + threadIdx.x;
  if (t >= NNZ) return;
  int i = PAT.i[t], j = PAT.j[t], slot = PAT.slot[t];
  int tr = 0;
  while (slot >= TRI.slot0[tr] + 2 * TRI.l3[tr] + 1) ++tr;
  int l1 = TRI.l1[tr], l2 = TRI.l2[tr], l3 = TRI.l3[tr];
  int a = i - l1 * l1, b = j - l2 * l2, c = slot - TRI.slot0[tr];
  URow u1 = u_row(l1, a), u2 = u_row(l2, b), u3 = u_row(l3, c);
  double sre = 0.0, sim = 0.0;
  for (int x = 0; x < u1.n; ++x)
    for (int y = 0; y < u2.n; ++y)
      for (int z = 0; z < u3.n; ++z) {
        int m1 = u1.m[x], m2 = u2.m[y], m3 = u3.m[z];
        if (m1 + m2 != m3) continue;
        double cg = cg_complex_d(l1, m1, l2, m2, l3, m3);
        if (cg == 0.0) continue;
        C2 t12 = cmul({u1.re[x], u1.im[x]}, {u2.re[y], u2.im[y]});
        C2 t123 = cmul(t12, {u3.re[z], -u3.im[z]});
        sre += t123.re * cg; sim += t123.im * cg;
      }
  cgv[t] = (float)(((l1 + l2 + l3) & 1) ? sim : sre);
}

// ---------------------------------------------------------------------------
// Real spherical harmonics l<=4 (matches reference formulas exactly)
// ---------------------------------------------------------------------------
DEVINL void sh25(float x, float y, float z, float* Y) {
  float x2 = x * x, y2 = y * y, z2 = z * z;
  Y[0] = 0.28209479177387814f;
  Y[1] = 0.4886025119029199f * y;
  Y[2] = 0.4886025119029199f * z;
  Y[3] = 0.4886025119029199f * x;
  Y[4] = 1.0925484305920792f * x * y;
  Y[5] = 1.0925484305920792f * y * z;
  Y[6] = 0.31539156525252005f * (3.0f * z2 - 1.0f);
  Y[7] = 1.0925484305920792f * x * z;
  Y[8] = 0.5462742152960396f * (x2 - y2);
  Y[9] = 0.5900435899266435f * y * (3.0f * x2 - y2);
  Y[10] = 2.890611442640554f * x * y * z;
  Y[11] = 0.4570457994644658f * y * (5.0f * z2 - 1.0f);
  Y[12] = 0.3731763325901154f * z * (5.0f * z2 - 3.0f);
  Y[13] = 0.4570457994644658f * x * (5.0f * z2 - 1.0f);
  Y[14] = 1.445305721320277f * z * (x2 - y2);
  Y[15] = 0.5900435899266435f * x * (x2 - 3.0f * y2);
  Y[16] = 2.5033429417967046f * x * y * (x2 - y2);
  Y[17] = 1.7701307697799304f * y * z * (3.0f * x2 - y2);
  Y[18] = 0.9461746957575601f * x * y * (7.0f * z2 - 1.0f);
  Y[19] = 0.6690465435572892f * y * z * (7.0f * z2 - 3.0f);
  Y[20] = 0.10578554691520431f * (35.0f * z2 * z2 - 30.0f * z2 + 3.0f);
  Y[21] = 0.6690465435572892f * x * z * (7.0f * z2 - 3.0f);
  Y[22] = 0.47308734787878004f * (x2 - y2) * (7.0f * z2 - 1.0f);
  Y[23] = 1.7701307697799304f * x * z * (x2 - 3.0f * y2);
  Y[24] = 0.6258357354491761f * (x2 * x2 - 6.0f * x2 * y2 + y2 * y2);
}

// ---------------------------------------------------------------------------
// CSR build kernels (segment offsets for idx_i)
// ---------------------------------------------------------------------------
__global__ void khist(const int* __restrict__ nbr, int* __restrict__ counts, int P) {
  int p = blockIdx.x * 256 + threadIdx.x;
  if (p < P) atomicAdd(&counts[nbr[p]], 1);
}

__global__ void kscan(const int* __restrict__ counts, int* __restrict__ offsets,
                      int* __restrict__ cursor, int A, int P) {
  __shared__ int sh[256];
  int t = threadIdx.x;
  int items = A / 256;   // 8 for A=2048
  int local[16];
  int sum = 0;
  for (int u = 0; u < items; ++u) { local[u] = sum; sum += counts[t * items + u]; }
  sh[t] = sum;
  __syncthreads();
  for (int off = 1; off < 256; off <<= 1) {
    int v = (t >= off) ? sh[t - off] : 0;
    __syncthreads();
    sh[t] += v;
    __syncthreads();
  }
  int base = sh[t] - sum;
  for (int u = 0; u < items; ++u) {
    int o = base + local[u];
    offsets[t * items + u] = o;
    cursor[t * items + u] = o;
  }
  if (t == 255) offsets[A] = P;
}

__global__ void kscat(const int* __restrict__ nbr, int* __restrict__ cursor,
                      int* __restrict__ plist, int P) {
  int p = blockIdx.x * 256 + threadIdx.x;
  if (p < P) {
    int a = nbr[p];
    int pos = atomicAdd(&cursor[a], 1);
    plist[pos] = p;
  }
}

// ---------------------------------------------------------------------------
// k1: per-pair radial vector  radial_t[c][p] = g(r,c)*env(r)*s_j[c]
// ---------------------------------------------------------------------------
__global__ __launch_bounds__(256) void k1(const int* __restrict__ Z,
                                          const int* __restrict__ nbr,
                                          const float* __restrict__ disp,
                                          const float* __restrict__ se,
                                          float* __restrict__ radial_t, int P) {
  int p = blockIdx.x * 256 + threadIdx.x;
  if (p >= P) return;
  int zj = Z[nbr[P + p]];
  float dx = disp[3 * p], dy = disp[3 * p + 1], dz = disp[3 * p + 2];
  float r = sqrtf(dx * dx + dy * dy + dz * dz + 1e-12f);
  const float RCUT = 5.0f;
  float env = 0.5f * (cosf(3.14159265358979f * fminf(r * (1.0f / RCUT), 1.0f)) + 1.0f);
  const float delta = RCUT / 63.0f;
  const float w = 0.5f / (delta * delta);
  const float4* s4 = (const float4*)(se + (size_t)zj * 64);
  for (int c = 0; c < 16; ++c) {
    float4 s = s4[c];
    float e0 = env * s.x, e1 = env * s.y, e2 = env * s.z, e3 = env * s.w;
    float c0 = (4 * c + 0) * delta, c1 = (4 * c + 1) * delta;
    float c2 = (4 * c + 2) * delta, c3 = (4 * c + 3) * delta;
    radial_t[(size_t)(4 * c + 0) * P + p] = expf(-w * (r - c0) * (r - c0)) * e0;
    radial_t[(size_t)(4 * c + 1) * P + p] = expf(-w * (r - c1) * (r - c1)) * e1;
    radial_t[(size_t)(4 * c + 2) * P + p] = expf(-w * (r - c2) * (r - c2)) * e2;
    radial_t[(size_t)(4 * c + 3) * P + p] = expf(-w * (r - c3) * (r - c3)) * e3;
  }
}

// ---------------------------------------------------------------------------
// k1b: embW[a][f] = (species_embed[Z[a]] @ Wt + bt)[f]
// ---------------------------------------------------------------------------
__global__ __launch_bounds__(256) void k1b(const int* __restrict__ Z,
                                           const float* __restrict__ se,
                                           const float* __restrict__ Wt,
                                           const float* __restrict__ bt,
                                           float* __restrict__ embW, int A) {
  int idx = blockIdx.x * 256 + threadIdx.x;
  if (idx >= A * 64) return;
  int a = idx >> 6, f = idx & 63;
  int z = Z[a];
  float acc = bt[f];
  for (int c = 0; c < 64; ++c)
    acc = fmaf(se[(size_t)z * 64 + c], Wt[(size_t)c * 64 + f], acc);
  embW[idx] = acc;
}

// ---------------------------------------------------------------------------
// k2: RV[which][p][g] = sum_c radial[p][c] * W[which][c][g]  (+ bias fold on l=0)
//   grid (P/64, 10), block 256 (4 waves, 16 pairs/wave), W_l staged in LDS,
//   radial read via wave-uniform scalar loads.
// ---------------------------------------------------------------------------
__global__ __launch_bounds__(256) void k2(const float* __restrict__ radial_t,
                                          const float* __restrict__ W1,
                                          const float* __restrict__ W2,
                                          const float* __restrict__ b1,
                                          const float* __restrict__ b2,
                                          float* __restrict__ RV, int P) {
  __shared__ float shW[64 * 64];
  int which = blockIdx.y;
  const float* Wsel = (which < 5) ? (W1 + (size_t)which * 4096)
                                  : (W2 + (size_t)(which - 5) * 4096);
  for (int rr = 0; rr < 16; ++rr)
    shW[rr * 256 + threadIdx.x] = Wsel[rr * 256 + threadIdx.x];
  __syncthreads();

  int g = threadIdx.x & 63;
  int wv = __builtin_amdgcn_readfirstlane(threadIdx.x >> 6);
  int p0 = blockIdx.x * 64 + wv * 16;

  float acc[16];
#pragma unroll
  for (int u = 0; u < 16; ++u) acc[u] = 0.f;

  for (int f = 0; f < 64; ++f) {
    float wf = shW[f * 64 + g];
    const float* rp = radial_t + (size_t)f * P + p0;
    float4 a0 = *(const float4*)(rp + 0);
    float4 a1 = *(const float4*)(rp + 4);
    float4 a2 = *(const float4*)(rp + 8);
    float4 a3 = *(const float4*)(rp + 12);
    acc[0]  = fmaf(a0.x, wf, acc[0]);  acc[1]  = fmaf(a0.y, wf, acc[1]);
    acc[2]  = fmaf(a0.z, wf, acc[2]);  acc[3]  = fmaf(a0.w, wf, acc[3]);
    acc[4]  = fmaf(a1.x, wf, acc[4]);  acc[5]  = fmaf(a1.y, wf, acc[5]);
    acc[6]  = fmaf(a1.z, wf, acc[6]);  acc[7]  = fmaf(a1.w, wf, acc[7]);
    acc[8]  = fmaf(a2.x, wf, acc[8]);  acc[9]  = fmaf(a2.y, wf, acc[9]);
    acc[10] = fmaf(a2.z, wf, acc[10]); acc[11] = fmaf(a2.w, wf, acc[11]);
    acc[12] = fmaf(a3.x, wf, acc[12]); acc[13] = fmaf(a3.y, wf, acc[13]);
    acc[14] = fmaf(a3.z, wf, acc[14]); acc[15] = fmaf(a3.w, wf, acc[15]);
  }
  if ((which % 5) == 0) {
    float bb = ((which == 0) ? b1[g] : b2[g]) * (float)(1.0 / 0.28209479177387814);
#pragma unroll
    for (int u = 0; u < 16; ++u) acc[u] += bb;
  }
#pragma unroll
  for (int u = 0; u < 16; ++u)
    RV[((size_t)which * P + (p0 + u)) * 64 + g] = acc[u];
}

// ---------------------------------------------------------------------------
// kT: one pair per thread; T[slot] = sum_nnz cg * Y_i * Y_j, chunked into
//   48 registers; fully unrolled compile-time pattern; float4 stores [g][p].
// ---------------------------------------------------------------------------
template <int C>
DEVINL void tchunk(const float* __restrict__ cgv, const float (&Y)[25],
                   float4* __restrict__ T4, int p, int P) {
  float acc[CHUNK];
#pragma unroll
  for (int s = 0; s < CHUNK; ++s) acc[s] = 0.f;
  constexpr int t0 = CB.b[C];
  constexpr int t1 = CB.b[C + 1];
#pragma unroll
  for (int t = t0; t < t1; ++t) {
    acc[PAT.slot[t] - C * CHUNK] =
        fmaf(cgv[t] * Y[PAT.i[t]], Y[PAT.j[t]], acc[PAT.slot[t] - C * CHUNK]);
  }
#pragma unroll
  for (int s = 0; s < CHUNK; s += 4) {
    T4[(size_t)((C * CHUNK + s) >> 2) * P + p] =
        make_float4(acc[s], acc[s + 1], acc[s + 2], acc[s + 3]);
  }
}

__global__ __launch_bounds__(256) void kT(const float* __restrict__ disp,
                                          const float* __restrict__ cgv,
                                          float* __restrict__ Tws, int P) {
  int p = blockIdx.x * 256 + threadIdx.x;
  if (p >= P) return;
  float dx = disp[3 * p], dy = disp[3 * p + 1], dz = disp[3 * p + 2];
  float r = sqrtf(dx * dx + dy * dy + dz * dz + 1e-12f);
  float inv = 1.0f / r;
  float Y[25];
  sh25(dx * inv, dy * inv, dz * inv, Y);
  float4* T4 = (float4*)Tws;
  tchunk<0>(cgv, Y, T4, p, P);
  tchunk<1>(cgv, Y, T4, p, P);
  tchunk<2>(cgv, Y, T4, p, P);
  tchunk<3>(cgv, Y, T4, p, P);
  tchunk<4>(cgv, Y, T4, p, P);
  tchunk<5>(cgv, Y, T4, p, P);
  tchunk<6>(cgv, Y, T4, p, P);
  tchunk<7>(cgv, Y, T4, p, P);
}

// ---------------------------------------------------------------------------
// k3: one wave per atom, lane = f. Accumulate over CSR pair list:
//   acc[k] += T_p[slot] * rv1[l1]*rv2[l2]; then *embW, +embW on k=0.
// ---------------------------------------------------------------------------
__global__ __launch_bounds__(64) void k3(const float* __restrict__ RV,
                                         const float* __restrict__ Tws,
                                         const float* __restrict__ embW,
                                         const int* __restrict__ offsets,
                                         const int* __restrict__ plist,
                                         float* __restrict__ out, int P) {
  int atom = blockIdx.x;
  int f = threadIdx.x;
  float acc[25];
#pragma unroll
  for (int k = 0; k < 25; ++k) acc[k] = 0.f;
  int beg = offsets[atom], end = offsets[atom + 1];
  const float4* T4 = (const float4*)Tws;
  for (int q = beg; q < end; ++q) {
    int p = plist[q];
    p = __builtin_amdgcn_readfirstlane(p);
    float rv1[5], rv2[5];
#pragma unroll
    for (int l = 0; l < 5; ++l) rv1[l] = RV[((size_t)l * P + p) * 64 + f];
#pragma unroll
    for (int l = 0; l < 5; ++l) rv2[l] = RV[((size_t)(5 + l) * P + p) * 64 + f];
    float prods[65];
#pragma unroll
    for (int t = 0; t < 65; ++t) prods[t] = rv1[TRI.l1[t]] * rv2[TRI.l2[t]];
#pragma unroll
    for (int g = 0; g < NSLOT4; ++g) {
      if (SLOT.k[g * 4] < 0 && SLOT.k[g * 4 + 1] < 0 &&
          SLOT.k[g * 4 + 2] < 0 && SLOT.k[g * 4 + 3] < 0)
        continue;
      float4 tv = T4[(size_t)g * P + p];
#pragma unroll
      for (int u = 0; u < 4; ++u) {
        int slot = g * 4 + u;
        if (SLOT.k[slot] >= 0) {
          float tvu = (u == 0 ? tv.x : u == 1 ? tv.y : u == 2 ? tv.z : tv.w);
          acc[SLOT.k[slot]] = fmaf(tvu, prods[SLOT.tri[slot]], acc[SLOT.k[slot]]);
        }
      }
    }
  }
  float e = embW[(size_t)atom * 64 + f];
#pragma unroll
  for (int k = 0; k < 25; ++k) {
    float v = fmaf(acc[k], e, (k == 0) ? e : 0.f);
    out[(size_t)atom * 1600 + (size_t)k * 64 + f] = v;
  }
}

// ---------------------------------------------------------------------------
// Launch
// ---------------------------------------------------------------------------
static inline size_t align256(size_t x) { return (x + 255) & ~(size_t)255; }

extern "C" void kernel_launch(void* const* d_in, const int* in_sizes, int n_in,
                              void* d_out, int out_size, void* d_ws, size_t ws_size,
                              hipStream_t stream) {
  const int*   Z    = (const int*)d_in[0];
  const float* disp = (const float*)d_in[1];
  const int*   nbr  = (const int*)d_in[2];
  const float* se   = (const float*)d_in[3];
  const float* Wt   = (const float*)d_in[4];
  const float* bt   = (const float*)d_in[5];
  const float* W1   = (const float*)d_in[6];
  const float* b1   = (const float*)d_in[7];
  const float* W2   = (const float*)d_in[8];
  const float* b2   = (const float*)d_in[9];
  float* out = (float*)d_out;

  const int A = in_sizes[0];
  const int P = in_sizes[1] / 3;

  char* ws = (char*)d_ws;
  size_t o = 0;
  float* radial_t = (float*)(ws + o); o += align256((size_t)64 * P * 4);
  float* RV       = (float*)(ws + o); o += align256((size_t)10 * P * 64 * 4);
  float* Tws      = (float*)(ws + o); o += align256((size_t)NSLOT4 * 4 * P * 4);
  float* embW     = (float*)(ws + o); o += align256((size_t)A * 64 * 4);
  float* cgv      = (float*)(ws + o); o += align256((size_t)NNZ * 4);
  int*   counts   = (int*)(ws + o);   o += align256((size_t)A * 4);
  int*   offsets  = (int*)(ws + o);   o += align256((size_t)(A + 1) * 4);
  int*   cursor   = (int*)(ws + o);   o += align256((size_t)A * 4);
  int*   plist    = (int*)(ws + o);   o += align256((size_t)P * 4);
  (void)ws_size; (void)n_in; (void)out_size;

  int pb = (P + 255) / 256;

  hipMemsetAsync(counts, 0, (size_t)A * 4, stream);
  khist<<<pb, 256, 0, stream>>>(nbr, counts, P);
  kscan<<<1, 256, 0, stream>>>(counts, offsets, cursor, A, P);
  kscat<<<pb, 256, 0, stream>>>(nbr, cursor, plist, P);
  kcg<<<(NNZ + 255) / 256, 256, 0, stream>>>(cgv);
  k1<<<pb, 256, 0, stream>>>(Z, nbr, disp, se, radial_t, P);
  k1b<<<(A * 64 + 255) / 256, 256, 0, stream>>>(Z, se, Wt, bt, embW, A);
  dim3 g2((unsigned)(P / 64), 10, 1);
  k2<<<g2, 256, 0, stream>>>(radial_t, W1, W2, b1, b2, RV, P);
  kT<<<pb, 256, 0, stream>>>(disp, cgv, Tws, P);
  k3<<<A, 64, 0, stream>>>(RV, Tws, embW, offsets, plist, out, P);
}

// Round 2
// 444.430 us; speedup vs baseline: 1.7815x; 1.7815x over previous
//
#include <hip/hip_runtime.h>

#define DEVINL __device__ __forceinline__

// ---------------------------------------------------------------------------
// Compile-time structure: allowed (l1,l2,l3) triples and CG sparsity pattern.
// CG *values* computed on device (kcg, verified in R1); per-triple scalar
// A(l1,l2,l3) derived on device by projection (kA2).
// ---------------------------------------------------------------------------
constexpr int LMAX = 4;

struct Triples {
  int n; int nslot;
  int l1[80], l2[80], l3[80], slot0[80];
};
constexpr Triples make_triples() {
  Triples T{}; T.n = 0; int s = 0;
  for (int a = 0; a <= LMAX; ++a)
    for (int b = 0; b <= LMAX; ++b)
      for (int c = 0; c <= LMAX; ++c) {
        int lo = a > b ? a - b : b - a;
        if (c < lo || c > a + b) continue;
        T.l1[T.n] = a; T.l2[T.n] = b; T.l3[T.n] = c; T.slot0[T.n] = s;
        s += 2 * c + 1; ++T.n;
      }
  T.nslot = s; return T;
}
constexpr Triples TRI = make_triples();
static_assert(TRI.n == 65, "triples");
static_assert(TRI.nslot == 375, "slots");

constexpr int cabs_(int x) { return x < 0 ? -x : x; }

constexpr int count_pat() {
  int cnt = 0;
  for (int t = 0; t < TRI.n; ++t) {
    int l1 = TRI.l1[t], l2 = TRI.l2[t], l3 = TRI.l3[t];
    for (int mc = -l3; mc <= l3; ++mc)
      for (int a = 0; a < 2 * l1 + 1; ++a)
        for (int b = 0; b < 2 * l2 + 1; ++b) {
          int Ma = a - l1, Mb = b - l2;
          int su = cabs_(Ma) + cabs_(Mb), di = cabs_(cabs_(Ma) - cabs_(Mb));
          if (cabs_(mc) == su || cabs_(mc) == di) ++cnt;
        }
  }
  return cnt;
}
constexpr int NNZ = count_pat();

template <int N> struct PatT { short i[N]; short j[N]; short slot[N]; };
constexpr PatT<NNZ> make_pat() {
  PatT<NNZ> P{}; int cnt = 0;
  for (int t = 0; t < TRI.n; ++t) {
    int l1 = TRI.l1[t], l2 = TRI.l2[t], l3 = TRI.l3[t];
    for (int mc = -l3; mc <= l3; ++mc) {
      int slot = TRI.slot0[t] + (mc + l3);
      for (int a = 0; a < 2 * l1 + 1; ++a)
        for (int b = 0; b < 2 * l2 + 1; ++b) {
          int Ma = a - l1, Mb = b - l2;
          int su = cabs_(Ma) + cabs_(Mb), di = cabs_(cabs_(Ma) - cabs_(Mb));
          if (cabs_(mc) == su || cabs_(mc) == di) {
            P.i[cnt] = (short)(l1 * l1 + a);
            P.j[cnt] = (short)(l2 * l2 + b);
            P.slot[cnt] = (short)slot;
            ++cnt;
          }
        }
    }
  }
  return P;
}
constexpr PatT<NNZ> PAT = make_pat();

// per-triple [begin,end) ranges into PAT (PAT is grouped by triple, in order)
struct TBT { int b[66]; };
constexpr TBT make_tb() {
  TBT B{};
  for (int t = 0; t <= TRI.n; ++t) {
    int s = (t < TRI.n) ? TRI.slot0[t] : TRI.nslot;
    int e = 0; while (e < NNZ && PAT.slot[e] < s) ++e;
    B.b[t] = e;
  }
  return B;
}
constexpr TBT TB = make_tb();

// even-parity triples (the only ones with nonzero A)
struct ETriT { int n; signed char l1[64], l2[64], l3[64], idx[64]; };
constexpr ETriT make_etri() {
  ETriT E{}; E.n = 0;
  for (int t = 0; t < TRI.n; ++t) {
    if (((TRI.l1[t] + TRI.l2[t] + TRI.l3[t]) & 1) == 0) {
      E.l1[E.n] = (signed char)TRI.l1[t];
      E.l2[E.n] = (signed char)TRI.l2[t];
      E.l3[E.n] = (signed char)TRI.l3[t];
      E.idx[E.n] = (signed char)t;
      ++E.n;
    }
  }
  return E;
}
constexpr ETriT ETRI = make_etri();
static_assert(ETRI.n == 42, "even triples");

// ---------------------------------------------------------------------------
// Device CG values (verified in R1)
// ---------------------------------------------------------------------------
DEVINL double dfact(int n) {
  const double F[14] = {1., 1., 2., 6., 24., 120., 720., 5040., 40320.,
                        362880., 3628800., 39916800., 479001600., 6227020800.};
  return F[n];
}

DEVINL double cg_complex_d(int l1, int m1, int l2, int m2, int l3, int m3) {
  if (m1 + m2 != m3) return 0.0;
  double pref = sqrt((2.0 * l3 + 1.0) * dfact(l1 + l2 - l3) * dfact(l1 - l2 + l3) *
                     dfact(-l1 + l2 + l3) / dfact(l1 + l2 + l3 + 1));
  pref *= sqrt(dfact(l1 + m1) * dfact(l1 - m1) * dfact(l2 + m2) * dfact(l2 - m2) *
               dfact(l3 + m3) * dfact(l3 - m3));
  double s = 0.0;
  for (int k = 0; k <= l1 + l2 - l3; ++k) {
    int d3 = l1 - m1 - k, d4 = l2 + m2 - k, d5 = l3 - l2 + m1 + k, d6 = l3 - l1 - m2 + k;
    if (d3 < 0 || d4 < 0 || d5 < 0 || d6 < 0) continue;
    double den = dfact(k) * dfact(l1 + l2 - l3 - k) * dfact(d3) * dfact(d4) *
                 dfact(d5) * dfact(d6);
    s += ((k & 1) ? -1.0 : 1.0) / den;
  }
  return pref * s;
}

struct C2 { double re, im; };
DEVINL C2 cmul(C2 x, C2 y) { return {x.re * y.re - x.im * y.im, x.re * y.im + x.im * y.re}; }

struct URow { int n; int m[2]; double re[2], im[2]; };
DEVINL URow u_row(int l, int a) {
  URow u{}; int ma = a - l;
  const double RS2 = 0.70710678118654752440;
  if (ma == 0) { u.n = 1; u.m[0] = 0; u.re[0] = 1.0; u.im[0] = 0.0; }
  else if (ma > 0) {
    u.n = 2;
    u.m[0] = ma;  u.re[0] = ((ma & 1) ? -RS2 : RS2); u.im[0] = 0.0;
    u.m[1] = -ma; u.re[1] = RS2;                     u.im[1] = 0.0;
  } else {
    int mm = -ma; u.n = 2;
    u.m[0] = -mm; u.re[0] = 0.0; u.im[0] = RS2;
    u.m[1] =  mm; u.re[1] = 0.0; u.im[1] = ((mm & 1) ? RS2 : -RS2);
  }
  return u;
}

__global__ void kcg(float* __restrict__ cgv) {
  int t = blockIdx.x * 256 + threadIdx.x;
  if (t >= NNZ) return;
  int i = PAT.i[t], j = PAT.j[t], slot = PAT.slot[t];
  int tr = 0;
  while (slot >= TRI.slot0[tr] + 2 * TRI.l3[tr] + 1) ++tr;
  int l1 = TRI.l1[tr], l2 = TRI.l2[tr], l3 = TRI.l3[tr];
  int a = i - l1 * l1, b = j - l2 * l2, c = slot - TRI.slot0[tr];
  URow u1 = u_row(l1, a), u2 = u_row(l2, b), u3 = u_row(l3, c);
  double sre = 0.0, sim = 0.0;
  for (int x = 0; x < u1.n; ++x)
    for (int y = 0; y < u2.n; ++y)
      for (int z = 0; z < u3.n; ++z) {
        int m1 = u1.m[x], m2 = u2.m[y], m3 = u3.m[z];
        if (m1 + m2 != m3) continue;
        double cg = cg_complex_d(l1, m1, l2, m2, l3, m3);
        if (cg == 0.0) continue;
        C2 t12 = cmul({u1.re[x], u1.im[x]}, {u2.re[y], u2.im[y]});
        C2 t123 = cmul(t12, {u3.re[z], -u3.im[z]});
        sre += t123.re * cg; sim += t123.im * cg;
      }
  cgv[t] = (float)(((l1 + l2 + l3) & 1) ? sim : sre);
}

// ---------------------------------------------------------------------------
// Real spherical harmonics l<=4
// ---------------------------------------------------------------------------
DEVINL void sh25(float x, float y, float z, float* Y) {
  float x2 = x * x, y2 = y * y, z2 = z * z;
  Y[0] = 0.28209479177387814f;
  Y[1] = 0.4886025119029199f * y;
  Y[2] = 0.4886025119029199f * z;
  Y[3] = 0.4886025119029199f * x;
  Y[4] = 1.0925484305920792f * x * y;
  Y[5] = 1.0925484305920792f * y * z;
  Y[6] = 0.31539156525252005f * (3.0f * z2 - 1.0f);
  Y[7] = 1.0925484305920792f * x * z;
  Y[8] = 0.5462742152960396f * (x2 - y2);
  Y[9] = 0.5900435899266435f * y * (3.0f * x2 - y2);
  Y[10] = 2.890611442640554f * x * y * z;
  Y[11] = 0.4570457994644658f * y * (5.0f * z2 - 1.0f);
  Y[12] = 0.3731763325901154f * z * (5.0f * z2 - 3.0f);
  Y[13] = 0.4570457994644658f * x * (5.0f * z2 - 1.0f);
  Y[14] = 1.445305721320277f * z * (x2 - y2);
  Y[15] = 0.5900435899266435f * x * (x2 - 3.0f * y2);
  Y[16] = 2.5033429417967046f * x * y * (x2 - y2);
  Y[17] = 1.7701307697799304f * y * z * (3.0f * x2 - y2);
  Y[18] = 0.9461746957575601f * x * y * (7.0f * z2 - 1.0f);
  Y[19] = 0.6690465435572892f * y * z * (7.0f * z2 - 3.0f);
  Y[20] = 0.10578554691520431f * (35.0f * z2 * z2 - 30.0f * z2 + 3.0f);
  Y[21] = 0.6690465435572892f * x * z * (7.0f * z2 - 3.0f);
  Y[22] = 0.47308734787878004f * (x2 - y2) * (7.0f * z2 - 1.0f);
  Y[23] = 1.7701307697799304f * x * z * (x2 - 3.0f * y2);
  Y[24] = 0.6258357354491761f * (x2 * x2 - 6.0f * x2 * y2 + y2 * y2);
}

// ---------------------------------------------------------------------------
// kA2: A[t] = projection of T(u0) onto Y_{l3}(u0); odd triples -> ~0.
// ---------------------------------------------------------------------------
__global__ void kA2(const float* __restrict__ cgv, float* __restrict__ Avec) {
  int t = threadIdx.x;
  if (t >= TRI.n) return;
  float ux = 0.437f, uy = -0.602f, uz = 0.668f;
  float inv = rsqrtf(ux * ux + uy * uy + uz * uz);
  float Y[25];
  sh25(ux * inv, uy * inv, uz * inv, Y);
  int l3 = TRI.l3[t], s0 = TRI.slot0[t];
  float den = 0.f;
  for (int m = 0; m < 2 * l3 + 1; ++m) { float yc = Y[l3 * l3 + m]; den += yc * yc; }
  float num = 0.f;
  for (int e = TB.b[t]; e < TB.b[t + 1]; ++e)
    num += cgv[e] * Y[PAT.i[e]] * Y[PAT.j[e]] * Y[l3 * l3 + (PAT.slot[e] - s0)];
  Avec[t] = num / den;
}

// ---------------------------------------------------------------------------
// CSR build kernels (segment offsets for idx_i)
// ---------------------------------------------------------------------------
__global__ void khist(const int* __restrict__ nbr, int* __restrict__ counts, int P) {
  int p = blockIdx.x * 256 + threadIdx.x;
  if (p < P) atomicAdd(&counts[nbr[p]], 1);
}

__global__ void kscan(const int* __restrict__ counts, int* __restrict__ offsets,
                      int* __restrict__ cursor, int A, int P) {
  __shared__ int sh[256];
  int t = threadIdx.x;
  int items = A / 256;
  int local[16];
  int sum = 0;
  for (int u = 0; u < items; ++u) { local[u] = sum; sum += counts[t * items + u]; }
  sh[t] = sum;
  __syncthreads();
  for (int off = 1; off < 256; off <<= 1) {
    int v = (t >= off) ? sh[t - off] : 0;
    __syncthreads();
    sh[t] += v;
    __syncthreads();
  }
  int base = sh[t] - sum;
  for (int u = 0; u < items; ++u) {
    int o = base + local[u];
    offsets[t * items + u] = o;
    cursor[t * items + u] = o;
  }
  if (t == 255) offsets[A] = P;
}

__global__ void kscat(const int* __restrict__ nbr, int* __restrict__ cursor,
                      int* __restrict__ plist, int P) {
  int p = blockIdx.x * 256 + threadIdx.x;
  if (p < P) {
    int a = nbr[p];
    int pos = atomicAdd(&cursor[a], 1);
    plist[pos] = p;
  }
}

// ---------------------------------------------------------------------------
// k1: radial_t[c][p] = g(r,c)*env(r)*s_j[c]
// ---------------------------------------------------------------------------
__global__ __launch_bounds__(256) void k1(const int* __restrict__ Z,
                                          const int* __restrict__ nbr,
                                          const float* __restrict__ disp,
                                          const float* __restrict__ se,
                                          float* __restrict__ radial_t, int P) {
  int p = blockIdx.x * 256 + threadIdx.x;
  if (p >= P) return;
  int zj = Z[nbr[P + p]];
  float dx = disp[3 * p], dy = disp[3 * p + 1], dz = disp[3 * p + 2];
  float r = sqrtf(dx * dx + dy * dy + dz * dz + 1e-12f);
  const float RCUT = 5.0f;
  float env = 0.5f * (__cosf(3.14159265358979f * fminf(r * (1.0f / RCUT), 1.0f)) + 1.0f);
  const float delta = RCUT / 63.0f;
  const float w = 0.5f / (delta * delta);
  const float4* s4 = (const float4*)(se + (size_t)zj * 64);
  for (int c = 0; c < 16; ++c) {
    float4 s = s4[c];
    float e0 = env * s.x, e1 = env * s.y, e2 = env * s.z, e3 = env * s.w;
    float c0 = (4 * c + 0) * delta, c1 = (4 * c + 1) * delta;
    float c2 = (4 * c + 2) * delta, c3 = (4 * c + 3) * delta;
    radial_t[(size_t)(4 * c + 0) * P + p] = __expf(-w * (r - c0) * (r - c0)) * e0;
    radial_t[(size_t)(4 * c + 1) * P + p] = __expf(-w * (r - c1) * (r - c1)) * e1;
    radial_t[(size_t)(4 * c + 2) * P + p] = __expf(-w * (r - c2) * (r - c2)) * e2;
    radial_t[(size_t)(4 * c + 3) * P + p] = __expf(-w * (r - c3) * (r - c3)) * e3;
  }
}

// ---------------------------------------------------------------------------
// k1b: embW[a][f] = (species_embed[Z[a]] @ Wt + bt)[f]
// ---------------------------------------------------------------------------
__global__ __launch_bounds__(256) void k1b(const int* __restrict__ Z,
                                           const float* __restrict__ se,
                                           const float* __restrict__ Wt,
                                           const float* __restrict__ bt,
                                           float* __restrict__ embW, int A) {
  int idx = blockIdx.x * 256 + threadIdx.x;
  if (idx >= A * 64) return;
  int a = idx >> 6, f = idx & 63;
  int z = Z[a];
  float acc = bt[f];
  for (int c = 0; c < 64; ++c)
    acc = fmaf(se[(size_t)z * 64 + c], Wt[(size_t)c * 64 + f], acc);
  embW[idx] = acc;
}

// ---------------------------------------------------------------------------
// k2G: fused GEMV + G.  Per wave: 8 pairs, lane = g (output feature).
//   rv1[l][u] = sum_c radial[c][p0+u] * W1[l][c][g]   (bias fold on l=0)
//   rv2 likewise per l2 (streamed), G[l3][u] += A(t)*rv1[l1][u]*rv2[u]
//   Gout[p][l3][g], 42 MB.
// ---------------------------------------------------------------------------
__global__ __launch_bounds__(256) void k2G(const float* __restrict__ radial_t,
                                           const float* __restrict__ W1,
                                           const float* __restrict__ W2,
                                           const float* __restrict__ b1,
                                           const float* __restrict__ b2,
                                           const float* __restrict__ Avec,
                                           float* __restrict__ Gout, int P) {
  __shared__ float shW[64 * 64];
  int g = threadIdx.x & 63;
  int wv = threadIdx.x >> 6;
  int p0 = blockIdx.x * 32 + wv * 8;
  const float invY0 = 3.5449077018110318f;  // 1/Y_00 = 2*sqrt(pi)

  float rv1[5][8];
  float G[5][8];
#pragma unroll
  for (int l = 0; l < 5; ++l)
#pragma unroll
    for (int u = 0; u < 8; ++u) G[l][u] = 0.f;

#pragma unroll
  for (int l = 0; l < 5; ++l) {
    __syncthreads();
    for (int i = 0; i < 16; ++i)
      shW[i * 256 + threadIdx.x] = W1[(size_t)l * 4096 + i * 256 + threadIdx.x];
    __syncthreads();
    float acc[8];
#pragma unroll
    for (int u = 0; u < 8; ++u) acc[u] = 0.f;
    for (int c = 0; c < 64; ++c) {
      float wf = shW[c * 64 + g];
      const float4* r4 = (const float4*)(radial_t + (size_t)c * P + p0);
      float4 x = r4[0], y = r4[1];
      acc[0] = fmaf(x.x, wf, acc[0]); acc[1] = fmaf(x.y, wf, acc[1]);
      acc[2] = fmaf(x.z, wf, acc[2]); acc[3] = fmaf(x.w, wf, acc[3]);
      acc[4] = fmaf(y.x, wf, acc[4]); acc[5] = fmaf(y.y, wf, acc[5]);
      acc[6] = fmaf(y.z, wf, acc[6]); acc[7] = fmaf(y.w, wf, acc[7]);
    }
    if (l == 0) {
      float bb = b1[g] * invY0;
#pragma unroll
      for (int u = 0; u < 8; ++u) acc[u] += bb;
    }
#pragma unroll
    for (int u = 0; u < 8; ++u) rv1[l][u] = acc[u];
  }

#pragma unroll
  for (int l2 = 0; l2 < 5; ++l2) {
    __syncthreads();
    for (int i = 0; i < 16; ++i)
      shW[i * 256 + threadIdx.x] = W2[(size_t)l2 * 4096 + i * 256 + threadIdx.x];
    __syncthreads();
    float acc[8];
#pragma unroll
    for (int u = 0; u < 8; ++u) acc[u] = 0.f;
    for (int c = 0; c < 64; ++c) {
      float wf = shW[c * 64 + g];
      const float4* r4 = (const float4*)(radial_t + (size_t)c * P + p0);
      float4 x = r4[0], y = r4[1];
      acc[0] = fmaf(x.x, wf, acc[0]); acc[1] = fmaf(x.y, wf, acc[1]);
      acc[2] = fmaf(x.z, wf, acc[2]); acc[3] = fmaf(x.w, wf, acc[3]);
      acc[4] = fmaf(y.x, wf, acc[4]); acc[5] = fmaf(y.y, wf, acc[5]);
      acc[6] = fmaf(y.z, wf, acc[6]); acc[7] = fmaf(y.w, wf, acc[7]);
    }
    if (l2 == 0) {
      float bb = b2[g] * invY0;
#pragma unroll
      for (int u = 0; u < 8; ++u) acc[u] += bb;
    }
#pragma unroll
    for (int e = 0; e < 42; ++e) {
      if ((int)ETRI.l2[e] == l2) {
        float At = Avec[(int)ETRI.idx[e]];
        const int l1 = ETRI.l1[e], l3 = ETRI.l3[e];
#pragma unroll
        for (int u = 0; u < 8; ++u)
          G[l3][u] = fmaf(At * rv1[l1][u], acc[u], G[l3][u]);
      }
    }
  }

#pragma unroll
  for (int u = 0; u < 8; ++u)
#pragma unroll
    for (int l3 = 0; l3 < 5; ++l3)
      Gout[((size_t)(p0 + u) * 5 + l3) * 64 + g] = G[l3][u];
}

// ---------------------------------------------------------------------------
// k3: one wave per atom, lane = f.
//   acc[k] += Y_k(u_p) * G[p][deg(k)][f]  over CSR pair list; epilogue *embW.
// ---------------------------------------------------------------------------
__global__ __launch_bounds__(64) void k3(const float* __restrict__ G,
                                         const float* __restrict__ disp,
                                         const float* __restrict__ embW,
                                         const int* __restrict__ offsets,
                                         const int* __restrict__ plist,
                                         float* __restrict__ out, int P) {
  int atom = blockIdx.x;
  int f = threadIdx.x;
  float acc[25];
#pragma unroll
  for (int k = 0; k < 25; ++k) acc[k] = 0.f;
  int beg = offsets[atom], end = offsets[atom + 1];
  for (int q = beg; q < end; ++q) {
    int p = __builtin_amdgcn_readfirstlane(plist[q]);
    float dx = disp[3 * p], dy = disp[3 * p + 1], dz = disp[3 * p + 2];
    float r = sqrtf(dx * dx + dy * dy + dz * dz + 1e-12f);
    float inv = 1.0f / r;
    float Y[25];
    sh25(dx * inv, dy * inv, dz * inv, Y);
    const float* Gp = G + (size_t)p * 320 + f;
    float g0 = Gp[0], g1 = Gp[64], g2 = Gp[128], g3 = Gp[192], g4 = Gp[256];
    acc[0] = fmaf(Y[0], g0, acc[0]);
#pragma unroll
    for (int k = 1; k < 4; ++k)  acc[k] = fmaf(Y[k], g1, acc[k]);
#pragma unroll
    for (int k = 4; k < 9; ++k)  acc[k] = fmaf(Y[k], g2, acc[k]);
#pragma unroll
    for (int k = 9; k < 16; ++k) acc[k] = fmaf(Y[k], g3, acc[k]);
#pragma unroll
    for (int k = 16; k < 25; ++k) acc[k] = fmaf(Y[k], g4, acc[k]);
  }
  float e = embW[(size_t)atom * 64 + f];
#pragma unroll
  for (int k = 0; k < 25; ++k) {
    float v = fmaf(acc[k], e, (k == 0) ? e : 0.f);
    out[(size_t)atom * 1600 + (size_t)k * 64 + f] = v;
  }
}

// ---------------------------------------------------------------------------
// Launch
// ---------------------------------------------------------------------------
static inline size_t align256(size_t x) { return (x + 255) & ~(size_t)255; }

extern "C" void kernel_launch(void* const* d_in, const int* in_sizes, int n_in,
                              void* d_out, int out_size, void* d_ws, size_t ws_size,
                              hipStream_t stream) {
  const int*   Z    = (const int*)d_in[0];
  const float* disp = (const float*)d_in[1];
  const int*   nbr  = (const int*)d_in[2];
  const float* se   = (const float*)d_in[3];
  const float* Wt   = (const float*)d_in[4];
  const float* bt   = (const float*)d_in[5];
  const float* W1   = (const float*)d_in[6];
  const float* b1   = (const float*)d_in[7];
  const float* W2   = (const float*)d_in[8];
  const float* b2   = (const float*)d_in[9];
  float* out = (float*)d_out;

  const int A = in_sizes[0];
  const int P = in_sizes[1] / 3;

  char* ws = (char*)d_ws;
  size_t o = 0;
  float* radial_t = (float*)(ws + o); o += align256((size_t)64 * P * 4);
  float* G        = (float*)(ws + o); o += align256((size_t)P * 5 * 64 * 4);
  float* embW     = (float*)(ws + o); o += align256((size_t)A * 64 * 4);
  float* cgv      = (float*)(ws + o); o += align256((size_t)NNZ * 4);
  float* Avec     = (float*)(ws + o); o += align256((size_t)TRI.n * 4);
  int*   counts   = (int*)(ws + o);   o += align256((size_t)A * 4);
  int*   offsets  = (int*)(ws + o);   o += align256((size_t)(A + 1) * 4);
  int*   cursor   = (int*)(ws + o);   o += align256((size_t)A * 4);
  int*   plist    = (int*)(ws + o);   o += align256((size_t)P * 4);
  (void)ws_size; (void)n_in; (void)out_size;

  int pb = (P + 255) / 256;

  hipMemsetAsync(counts, 0, (size_t)A * 4, stream);
  khist<<<pb, 256, 0, stream>>>(nbr, counts, P);
  kscan<<<1, 256, 0, stream>>>(counts, offsets, cursor, A, P);
  kscat<<<pb, 256, 0, stream>>>(nbr, cursor, plist, P);
  kcg<<<(NNZ + 255) / 256, 256, 0, stream>>>(cgv);
  kA2<<<1, 128, 0, stream>>>(cgv, Avec);
  k1<<<pb, 256, 0, stream>>>(Z, nbr, disp, se, radial_t, P);
  k1b<<<(A * 64 + 255) / 256, 256, 0, stream>>>(Z, se, Wt, bt, embW, A);
  k2G<<<P / 32, 256, 0, stream>>>(radial_t, W1, W2, b1, b2, Avec, G, P);
  k3<<<A, 64, 0, stream>>>(G, disp, embW, offsets, plist, out, P);
}

// Round 3
// 177.685 us; speedup vs baseline: 4.4559x; 2.5012x over previous
//
#include <hip/hip_runtime.h>

#define DEVINL __device__ __forceinline__

// ===========================================================================
// Compile-time math: triples, real-CG entries, and the per-triple scalar A
// (T_p[(l1,l2,l3),m] = A(l1,l2,l3) * Y_{l3,m}(u_p); odd-parity A == 0).
// Verified against device-computed CG in R1/R2 (absmax 9.8e-4).
// ===========================================================================
constexpr int LMAX = 4;

struct Triples { int n; int l1[80], l2[80], l3[80]; };
constexpr Triples make_triples() {
  Triples T{}; T.n = 0;
  for (int a = 0; a <= LMAX; ++a)
    for (int b = 0; b <= LMAX; ++b)
      for (int c = 0; c <= LMAX; ++c) {
        int lo = a > b ? a - b : b - a;
        if (c < lo || c > a + b) continue;
        T.l1[T.n] = a; T.l2[T.n] = b; T.l3[T.n] = c; ++T.n;
      }
  return T;
}
constexpr Triples TRI = make_triples();
static_assert(TRI.n == 65, "triples");

// even-parity triples (only ones with A != 0)
struct ETriT { int n; signed char l1[48], l2[48], l3[48]; };
constexpr ETriT make_etri() {
  ETriT E{}; E.n = 0;
  for (int t = 0; t < TRI.n; ++t)
    if (((TRI.l1[t] + TRI.l2[t] + TRI.l3[t]) & 1) == 0) {
      E.l1[E.n] = (signed char)TRI.l1[t];
      E.l2[E.n] = (signed char)TRI.l2[t];
      E.l3[E.n] = (signed char)TRI.l3[t];
      ++E.n;
    }
  return E;
}
constexpr ETriT ETRI = make_etri();
static_assert(ETRI.n == 42, "even triples");

constexpr double FT[14] = {1., 1., 2., 6., 24., 120., 720., 5040., 40320.,
                           362880., 3628800., 39916800., 479001600., 6227020800.};

constexpr double csqrt(double x) {
  if (x <= 0.0) return 0.0;
  double y = 1.0;
  while (y * y < x) y *= 2.0;
  for (int i = 0; i < 30; ++i) y = 0.5 * (y + x / y);
  return y;
}

constexpr double cg_complex(int l1, int m1, int l2, int m2, int l3, int m3) {
  if (m1 + m2 != m3) return 0.0;
  double pref = csqrt((2.0 * l3 + 1.0) * FT[l1 + l2 - l3] * FT[l1 - l2 + l3] *
                      FT[-l1 + l2 + l3] / FT[l1 + l2 + l3 + 1]);
  pref *= csqrt(FT[l1 + m1] * FT[l1 - m1] * FT[l2 + m2] * FT[l2 - m2] *
                FT[l3 + m3] * FT[l3 - m3]);
  double s = 0.0;
  for (int k = 0; k <= l1 + l2 - l3; ++k) {
    int d3 = l1 - m1 - k, d4 = l2 + m2 - k, d5 = l3 - l2 + m1 + k, d6 = l3 - l1 - m2 + k;
    if (d3 < 0 || d4 < 0 || d5 < 0 || d6 < 0) continue;
    double den = FT[k] * FT[l1 + l2 - l3 - k] * FT[d3] * FT[d4] * FT[d5] * FT[d6];
    s += ((k & 1) ? -1.0 : 1.0) / den;
  }
  return pref * s;
}

struct CURow { int n; int m[2]; double re[2], im[2]; };
constexpr CURow cu_row(int l, int a) {
  CURow u{}; int ma = a - l;
  const double RS2 = 0.70710678118654752440;
  if (ma == 0) { u.n = 1; u.m[0] = 0; u.re[0] = 1.0; u.im[0] = 0.0; }
  else if (ma > 0) {
    u.n = 2;
    u.m[0] = ma;  u.re[0] = ((ma & 1) ? -RS2 : RS2); u.im[0] = 0.0;
    u.m[1] = -ma; u.re[1] = RS2;                     u.im[1] = 0.0;
  } else {
    int mm = -ma; u.n = 2;
    u.m[0] = -mm; u.re[0] = 0.0; u.im[0] = RS2;
    u.m[1] =  mm; u.re[1] = 0.0; u.im[1] = ((mm & 1) ? RS2 : -RS2);
  }
  return u;
}

constexpr double real_cg_entry(int l1, int a, int l2, int b, int l3, int c) {
  CURow u1 = cu_row(l1, a), u2 = cu_row(l2, b), u3 = cu_row(l3, c);
  double sre = 0.0, sim = 0.0;
  for (int x = 0; x < u1.n; ++x)
    for (int y = 0; y < u2.n; ++y)
      for (int z = 0; z < u3.n; ++z) {
        int m1 = u1.m[x], m2 = u2.m[y], m3 = u3.m[z];
        if (m1 + m2 != m3) continue;
        double cg = cg_complex(l1, m1, l2, m2, l3, m3);
        if (cg == 0.0) continue;
        double are = u1.re[x], aim = u1.im[x], bre = u2.re[y], bim = u2.im[y];
        double pre = are * bre - aim * bim, pim = are * bim + aim * bre;
        double cre = u3.re[z], cim = -u3.im[z];
        sre += (pre * cre - pim * cim) * cg;
        sim += (pre * cim + pim * cre) * cg;
      }
  return ((l1 + l2 + l3) & 1) ? sim : sre;
}

struct Y25D { double y[25]; };
constexpr Y25D csh25(double x, double y, double z) {
  Y25D Y{};
  double x2 = x * x, y2 = y * y, z2 = z * z;
  Y.y[0] = 0.28209479177387814;
  Y.y[1] = 0.4886025119029199 * y;
  Y.y[2] = 0.4886025119029199 * z;
  Y.y[3] = 0.4886025119029199 * x;
  Y.y[4] = 1.0925484305920792 * x * y;
  Y.y[5] = 1.0925484305920792 * y * z;
  Y.y[6] = 0.31539156525252005 * (3.0 * z2 - 1.0);
  Y.y[7] = 1.0925484305920792 * x * z;
  Y.y[8] = 0.5462742152960396 * (x2 - y2);
  Y.y[9] = 0.5900435899266435 * y * (3.0 * x2 - y2);
  Y.y[10] = 2.890611442640554 * x * y * z;
  Y.y[11] = 0.4570457994644658 * y * (5.0 * z2 - 1.0);
  Y.y[12] = 0.3731763325901154 * z * (5.0 * z2 - 3.0);
  Y.y[13] = 0.4570457994644658 * x * (5.0 * z2 - 1.0);
  Y.y[14] = 1.445305721320277 * z * (x2 - y2);
  Y.y[15] = 0.5900435899266435 * x * (x2 - 3.0 * y2);
  Y.y[16] = 2.5033429417967046 * x * y * (x2 - y2);
  Y.y[17] = 1.7701307697799304 * y * z * (3.0 * x2 - y2);
  Y.y[18] = 0.9461746957575601 * x * y * (7.0 * z2 - 1.0);
  Y.y[19] = 0.6690465435572892 * y * z * (7.0 * z2 - 3.0);
  Y.y[20] = 0.10578554691520431 * (35.0 * z2 * z2 - 30.0 * z2 + 3.0);
  Y.y[21] = 0.6690465435572892 * x * z * (7.0 * z2 - 3.0);
  Y.y[22] = 0.47308734787878004 * (x2 - y2) * (7.0 * z2 - 1.0);
  Y.y[23] = 1.7701307697799304 * x * z * (x2 - 3.0 * y2);
  Y.y[24] = 0.6258357354491761 * (x2 * x2 - 6.0 * x2 * y2 + y2 * y2);
  return Y;
}

// A for even-triple e via single-m ratio at a generic direction (exact identity)
constexpr double compute_A_even(int e) {
  int l1 = ETRI.l1[e], l2 = ETRI.l2[e], l3 = ETRI.l3[e];
  double ux = 0.437, uy = -0.602, uz = 0.668;
  double n = csqrt(ux * ux + uy * uy + uz * uz);
  Y25D Y = csh25(ux / n, uy / n, uz / n);
  int c0 = 2 * l3;  // m = +l3 component (nonzero at this direction)
  double den = Y.y[l3 * l3 + c0];
  double num = 0.0;
  for (int a = 0; a < 2 * l1 + 1; ++a)
    for (int b = 0; b < 2 * l2 + 1; ++b) {
      double v = real_cg_entry(l1, a, l2, b, l3, c0);
      if (v != 0.0) num += v * Y.y[l1 * l1 + a] * Y.y[l2 * l2 + b];
    }
  return num / den;
}

// one constant-evaluation per triple (keeps each under the constexpr-step cap)
template <int E> inline constexpr float A_of = (float)compute_A_even(E);
constexpr float AT42[42] = {
    A_of<0>,  A_of<1>,  A_of<2>,  A_of<3>,  A_of<4>,  A_of<5>,  A_of<6>,
    A_of<7>,  A_of<8>,  A_of<9>,  A_of<10>, A_of<11>, A_of<12>, A_of<13>,
    A_of<14>, A_of<15>, A_of<16>, A_of<17>, A_of<18>, A_of<19>, A_of<20>,
    A_of<21>, A_of<22>, A_of<23>, A_of<24>, A_of<25>, A_of<26>, A_of<27>,
    A_of<28>, A_of<29>, A_of<30>, A_of<31>, A_of<32>, A_of<33>, A_of<34>,
    A_of<35>, A_of<36>, A_of<37>, A_of<38>, A_of<39>, A_of<40>, A_of<41>};

// ===========================================================================
// Device helpers
// ===========================================================================
DEVINL void sh25(float x, float y, float z, float* Y) {
  float x2 = x * x, y2 = y * y, z2 = z * z;
  Y[0] = 0.28209479177387814f;
  Y[1] = 0.4886025119029199f * y;
  Y[2] = 0.4886025119029199f * z;
  Y[3] = 0.4886025119029199f * x;
  Y[4] = 1.0925484305920792f * x * y;
  Y[5] = 1.0925484305920792f * y * z;
  Y[6] = 0.31539156525252005f * (3.0f * z2 - 1.0f);
  Y[7] = 1.0925484305920792f * x * z;
  Y[8] = 0.5462742152960396f * (x2 - y2);
  Y[9] = 0.5900435899266435f * y * (3.0f * x2 - y2);
  Y[10] = 2.890611442640554f * x * y * z;
  Y[11] = 0.4570457994644658f * y * (5.0f * z2 - 1.0f);
  Y[12] = 0.3731763325901154f * z * (5.0f * z2 - 3.0f);
  Y[13] = 0.4570457994644658f * x * (5.0f * z2 - 1.0f);
  Y[14] = 1.445305721320277f * z * (x2 - y2);
  Y[15] = 0.5900435899266435f * x * (x2 - 3.0f * y2);
  Y[16] = 2.5033429417967046f * x * y * (x2 - y2);
  Y[17] = 1.7701307697799304f * y * z * (3.0f * x2 - y2);
  Y[18] = 0.9461746957575601f * x * y * (7.0f * z2 - 1.0f);
  Y[19] = 0.6690465435572892f * y * z * (7.0f * z2 - 3.0f);
  Y[20] = 0.10578554691520431f * (35.0f * z2 * z2 - 30.0f * z2 + 3.0f);
  Y[21] = 0.6690465435572892f * x * z * (7.0f * z2 - 3.0f);
  Y[22] = 0.47308734787878004f * (x2 - y2) * (7.0f * z2 - 1.0f);
  Y[23] = 1.7701307697799304f * x * z * (x2 - 3.0f * y2);
  Y[24] = 0.6258357354491761f * (x2 * x2 - 6.0f * x2 * y2 + y2 * y2);
}

// ===========================================================================
// CSR build (segment offsets for idx_i)
// ===========================================================================
__global__ void khist(const int* __restrict__ nbr, int* __restrict__ counts, int P) {
  int p = blockIdx.x * 256 + threadIdx.x;
  if (p < P) atomicAdd(&counts[nbr[p]], 1);
}

__global__ void kscan(const int* __restrict__ counts, int* __restrict__ offsets,
                      int* __restrict__ cursor, int A, int P) {
  __shared__ int sh[256];
  int t = threadIdx.x;
  int items = A / 256;
  int local[16];
  int sum = 0;
  for (int u = 0; u < items; ++u) { local[u] = sum; sum += counts[t * items + u]; }
  sh[t] = sum;
  __syncthreads();
  for (int off = 1; off < 256; off <<= 1) {
    int v = (t >= off) ? sh[t - off] : 0;
    __syncthreads();
    sh[t] += v;
    __syncthreads();
  }
  int base = sh[t] - sum;
  for (int u = 0; u < items; ++u) {
    int o = base + local[u];
    offsets[t * items + u] = o;
    cursor[t * items + u] = o;
  }
  if (t == 255) offsets[A] = P;
}

__global__ void kscat(const int* __restrict__ nbr, int* __restrict__ cursor,
                      int* __restrict__ plist, int P) {
  int p = blockIdx.x * 256 + threadIdx.x;
  if (p < P) {
    int a = nbr[p];
    int pos = atomicAdd(&cursor[a], 1);
    plist[pos] = p;
  }
}

// ===========================================================================
// k2G: fused radial + dual-GEMV + tensor-contraction collapse.
// Block = 256 threads (4 waves), 32 pairs. Radial tile computed into LDS
// (each value once), W rows read coalesced from L1, rad via broadcast b128.
//   Gout[p][l3][g], 41 MB.
// ===========================================================================
__global__ __launch_bounds__(256) void k2G(const int* __restrict__ Z,
                                           const int* __restrict__ nbr,
                                           const float* __restrict__ disp,
                                           const float* __restrict__ se,
                                           const float* __restrict__ W1,
                                           const float* __restrict__ W2,
                                           const float* __restrict__ b1,
                                           const float* __restrict__ b2,
                                           float* __restrict__ Gout, int P) {
  __shared__ float rad[64 * 36];  // [c][pair], stride 36 keeps b128 16B-aligned
  int p0 = blockIdx.x * 32;
  int t = threadIdx.x;
  {
    int pl = t >> 3, q = t & 7;  // pair-local, c-octet
    int p = p0 + pl;
    int zj = Z[nbr[P + p]];
    float dx = disp[3 * p], dy = disp[3 * p + 1], dz = disp[3 * p + 2];
    float r = sqrtf(dx * dx + dy * dy + dz * dz + 1e-12f);
    float env = 0.5f * (__cosf(3.14159265358979f * fminf(r * 0.2f, 1.0f)) + 1.0f);
    const float delta = 5.0f / 63.0f;
    const float w = 0.5f / (delta * delta);
    const float4* s4 = (const float4*)(se + (size_t)zj * 64);
    float4 sa = s4[q * 2], sb = s4[q * 2 + 1];
    float sv[8] = {sa.x, sa.y, sa.z, sa.w, sb.x, sb.y, sb.z, sb.w};
    int c0 = q * 8;
#pragma unroll
    for (int i = 0; i < 8; ++i) {
      float d = r - (float)(c0 + i) * delta;
      rad[(c0 + i) * 36 + pl] = __expf(-w * d * d) * env * sv[i];
    }
  }
  __syncthreads();

  int g = t & 63;
  int u0 = (t >> 6) * 8;  // 8 pairs per wave
  const float invY0 = 3.5449077018110318f;  // 1/Y_00

  float rv1[5][8];
#pragma unroll
  for (int l = 0; l < 5; ++l) {
    float acc[8] = {0.f, 0.f, 0.f, 0.f, 0.f, 0.f, 0.f, 0.f};
    const float* Wl = W1 + (size_t)l * 4096 + g;
#pragma unroll 4
    for (int c = 0; c < 64; ++c) {
      float wf = Wl[c * 64];
      const float4* rr = (const float4*)(rad + c * 36 + u0);
      float4 r0 = rr[0], r1 = rr[1];
      acc[0] = fmaf(r0.x, wf, acc[0]); acc[1] = fmaf(r0.y, wf, acc[1]);
      acc[2] = fmaf(r0.z, wf, acc[2]); acc[3] = fmaf(r0.w, wf, acc[3]);
      acc[4] = fmaf(r1.x, wf, acc[4]); acc[5] = fmaf(r1.y, wf, acc[5]);
      acc[6] = fmaf(r1.z, wf, acc[6]); acc[7] = fmaf(r1.w, wf, acc[7]);
    }
    if (l == 0) {
      float bb = b1[g] * invY0;
#pragma unroll
      for (int u = 0; u < 8; ++u) acc[u] += bb;
    }
#pragma unroll
    for (int u = 0; u < 8; ++u) rv1[l][u] = acc[u];
  }

  float Gacc[5][8];
#pragma unroll
  for (int l = 0; l < 5; ++l)
#pragma unroll
    for (int u = 0; u < 8; ++u) Gacc[l][u] = 0.f;

#pragma unroll
  for (int l2 = 0; l2 < 5; ++l2) {
    float acc[8] = {0.f, 0.f, 0.f, 0.f, 0.f, 0.f, 0.f, 0.f};
    const float* Wl = W2 + (size_t)l2 * 4096 + g;
#pragma unroll 4
    for (int c = 0; c < 64; ++c) {
      float wf = Wl[c * 64];
      const float4* rr = (const float4*)(rad + c * 36 + u0);
      float4 r0 = rr[0], r1 = rr[1];
      acc[0] = fmaf(r0.x, wf, acc[0]); acc[1] = fmaf(r0.y, wf, acc[1]);
      acc[2] = fmaf(r0.z, wf, acc[2]); acc[3] = fmaf(r0.w, wf, acc[3]);
      acc[4] = fmaf(r1.x, wf, acc[4]); acc[5] = fmaf(r1.y, wf, acc[5]);
      acc[6] = fmaf(r1.z, wf, acc[6]); acc[7] = fmaf(r1.w, wf, acc[7]);
    }
    if (l2 == 0) {
      float bb = b2[g] * invY0;
#pragma unroll
      for (int u = 0; u < 8; ++u) acc[u] += bb;
    }
#pragma unroll
    for (int e = 0; e < 42; ++e) {
      if ((int)ETRI.l2[e] != l2) continue;
      const float At = AT42[e];
      const int l1 = ETRI.l1[e], l3 = ETRI.l3[e];
#pragma unroll
      for (int u = 0; u < 8; ++u)
        Gacc[l3][u] = fmaf(At * rv1[l1][u], acc[u], Gacc[l3][u]);
    }
  }

#pragma unroll
  for (int u = 0; u < 8; ++u) {
    float* op = Gout + (size_t)(p0 + u0 + u) * 320 + g;
#pragma unroll
    for (int l3 = 0; l3 < 5; ++l3) op[l3 * 64] = Gacc[l3][u];
  }
}

// ===========================================================================
// k3: one wave per atom, lane = f. Software-pipelined pair loop; emb fused.
// ===========================================================================
__global__ __launch_bounds__(64) void k3(const float* __restrict__ G,
                                         const float* __restrict__ disp,
                                         const int* __restrict__ Z,
                                         const float* __restrict__ se,
                                         const float* __restrict__ Wt,
                                         const float* __restrict__ bt,
                                         const int* __restrict__ offsets,
                                         const int* __restrict__ plist,
                                         float* __restrict__ out, int P) {
  int atom = blockIdx.x;
  int f = threadIdx.x;
  float acc[25];
#pragma unroll
  for (int k = 0; k < 25; ++k) acc[k] = 0.f;
  int beg = offsets[atom], end = offsets[atom + 1];

  float cdx = 0, cdy = 0, cdz = 0, cg0 = 0, cg1 = 0, cg2 = 0, cg3 = 0, cg4 = 0;
  if (beg < end) {
    int p = __builtin_amdgcn_readfirstlane(plist[beg]);
    cdx = disp[3 * p]; cdy = disp[3 * p + 1]; cdz = disp[3 * p + 2];
    const float* Gp = G + (size_t)p * 320 + f;
    cg0 = Gp[0]; cg1 = Gp[64]; cg2 = Gp[128]; cg3 = Gp[192]; cg4 = Gp[256];
  }
  for (int q = beg; q < end; ++q) {
    float dx = cdx, dy = cdy, dz = cdz;
    float g0 = cg0, g1 = cg1, g2 = cg2, g3 = cg3, g4 = cg4;
    if (q + 1 < end) {
      int p = __builtin_amdgcn_readfirstlane(plist[q + 1]);
      cdx = disp[3 * p]; cdy = disp[3 * p + 1]; cdz = disp[3 * p + 2];
      const float* Gp = G + (size_t)p * 320 + f;
      cg0 = Gp[0]; cg1 = Gp[64]; cg2 = Gp[128]; cg3 = Gp[192]; cg4 = Gp[256];
    }
    float r = sqrtf(dx * dx + dy * dy + dz * dz + 1e-12f);
    float inv = 1.0f / r;
    float Y[25];
    sh25(dx * inv, dy * inv, dz * inv, Y);
    acc[0] = fmaf(Y[0], g0, acc[0]);
#pragma unroll
    for (int k = 1; k < 4; ++k)   acc[k] = fmaf(Y[k], g1, acc[k]);
#pragma unroll
    for (int k = 4; k < 9; ++k)   acc[k] = fmaf(Y[k], g2, acc[k]);
#pragma unroll
    for (int k = 9; k < 16; ++k)  acc[k] = fmaf(Y[k], g3, acc[k]);
#pragma unroll
    for (int k = 16; k < 25; ++k) acc[k] = fmaf(Y[k], g4, acc[k]);
  }

  // fused emb row: (se[Z[atom]] @ Wt + bt)[f]
  int z = Z[atom];
  float e = bt[f];
  for (int c = 0; c < 64; ++c)
    e = fmaf(se[(size_t)z * 64 + c], Wt[(size_t)c * 64 + f], e);

#pragma unroll
  for (int k = 0; k < 25; ++k)
    out[(size_t)atom * 1600 + (size_t)k * 64 + f] = fmaf(acc[k], e, (k == 0) ? e : 0.f);
}

// ===========================================================================
// Launch
// ===========================================================================
static inline size_t align256(size_t x) { return (x + 255) & ~(size_t)255; }

extern "C" void kernel_launch(void* const* d_in, const int* in_sizes, int n_in,
                              void* d_out, int out_size, void* d_ws, size_t ws_size,
                              hipStream_t stream) {
  const int*   Z    = (const int*)d_in[0];
  const float* disp = (const float*)d_in[1];
  const int*   nbr  = (const int*)d_in[2];
  const float* se   = (const float*)d_in[3];
  const float* Wt   = (const float*)d_in[4];
  const float* bt   = (const float*)d_in[5];
  const float* W1   = (const float*)d_in[6];
  const float* b1   = (const float*)d_in[7];
  const float* W2   = (const float*)d_in[8];
  const float* b2   = (const float*)d_in[9];
  float* out = (float*)d_out;

  const int A = in_sizes[0];
  const int P = in_sizes[1] / 3;

  char* ws = (char*)d_ws;
  size_t o = 0;
  float* G       = (float*)(ws + o); o += align256((size_t)P * 5 * 64 * 4);
  int*   counts  = (int*)(ws + o);   o += align256((size_t)A * 4);
  int*   offsets = (int*)(ws + o);   o += align256((size_t)(A + 1) * 4);
  int*   cursor  = (int*)(ws + o);   o += align256((size_t)A * 4);
  int*   plist   = (int*)(ws + o);   o += align256((size_t)P * 4);
  (void)ws_size; (void)n_in; (void)out_size;

  int pb = (P + 255) / 256;

  hipMemsetAsync(counts, 0, (size_t)A * 4, stream);
  khist<<<pb, 256, 0, stream>>>(nbr, counts, P);
  kscan<<<1, 256, 0, stream>>>(counts, offsets, cursor, A, P);
  kscat<<<pb, 256, 0, stream>>>(nbr, cursor, plist, P);
  k2G<<<P / 32, 256, 0, stream>>>(Z, nbr, disp, se, W1, W2, b1, b2, G, P);
  k3<<<A, 64, 0, stream>>>(G, disp, Z, se, Wt, bt, offsets, plist, out, P);
}

// Round 4
// 135.554 us; speedup vs baseline: 5.8408x; 1.3108x over previous
//
#include <hip/hip_runtime.h>

#define DEVINL __device__ __forceinline__

typedef __attribute__((ext_vector_type(8))) short bf16x8;
typedef __attribute__((ext_vector_type(4))) float f32x4;

// ===========================================================================
// Compile-time math: even-parity triples (l1,l2,l3) and scalar A per triple.
// (T_p[(l1,l2,l3),m] = A * Y_{l3,m}(u_p); odd-parity A == 0.)  Verified R3.
// ===========================================================================
constexpr int LMAX = 4;

struct Triples { int n; int l1[80], l2[80], l3[80]; };
constexpr Triples make_triples() {
  Triples T{}; T.n = 0;
  for (int a = 0; a <= LMAX; ++a)
    for (int b = 0; b <= LMAX; ++b)
      for (int c = 0; c <= LMAX; ++c) {
        int lo = a > b ? a - b : b - a;
        if (c < lo || c > a + b) continue;
        T.l1[T.n] = a; T.l2[T.n] = b; T.l3[T.n] = c; ++T.n;
      }
  return T;
}
constexpr Triples TRI = make_triples();
static_assert(TRI.n == 65, "triples");

struct ETriT { int n; signed char l1[48], l2[48], l3[48]; };
constexpr ETriT make_etri() {
  ETriT E{}; E.n = 0;
  for (int t = 0; t < TRI.n; ++t)
    if (((TRI.l1[t] + TRI.l2[t] + TRI.l3[t]) & 1) == 0) {
      E.l1[E.n] = (signed char)TRI.l1[t];
      E.l2[E.n] = (signed char)TRI.l2[t];
      E.l3[E.n] = (signed char)TRI.l3[t];
      ++E.n;
    }
  return E;
}
constexpr ETriT ETRI = make_etri();
static_assert(ETRI.n == 42, "even triples");

constexpr double FT[14] = {1., 1., 2., 6., 24., 120., 720., 5040., 40320.,
                           362880., 3628800., 39916800., 479001600., 6227020800.};

constexpr double csqrt(double x) {
  if (x <= 0.0) return 0.0;
  double y = 1.0;
  while (y * y < x) y *= 2.0;
  for (int i = 0; i < 30; ++i) y = 0.5 * (y + x / y);
  return y;
}

constexpr double cg_complex(int l1, int m1, int l2, int m2, int l3, int m3) {
  if (m1 + m2 != m3) return 0.0;
  double pref = csqrt((2.0 * l3 + 1.0) * FT[l1 + l2 - l3] * FT[l1 - l2 + l3] *
                      FT[-l1 + l2 + l3] / FT[l1 + l2 + l3 + 1]);
  pref *= csqrt(FT[l1 + m1] * FT[l1 - m1] * FT[l2 + m2] * FT[l2 - m2] *
                FT[l3 + m3] * FT[l3 - m3]);
  double s = 0.0;
  for (int k = 0; k <= l1 + l2 - l3; ++k) {
    int d3 = l1 - m1 - k, d4 = l2 + m2 - k, d5 = l3 - l2 + m1 + k, d6 = l3 - l1 - m2 + k;
    if (d3 < 0 || d4 < 0 || d5 < 0 || d6 < 0) continue;
    double den = FT[k] * FT[l1 + l2 - l3 - k] * FT[d3] * FT[d4] * FT[d5] * FT[d6];
    s += ((k & 1) ? -1.0 : 1.0) / den;
  }
  return pref * s;
}

struct CURow { int n; int m[2]; double re[2], im[2]; };
constexpr CURow cu_row(int l, int a) {
  CURow u{}; int ma = a - l;
  const double RS2 = 0.70710678118654752440;
  if (ma == 0) { u.n = 1; u.m[0] = 0; u.re[0] = 1.0; u.im[0] = 0.0; }
  else if (ma > 0) {
    u.n = 2;
    u.m[0] = ma;  u.re[0] = ((ma & 1) ? -RS2 : RS2); u.im[0] = 0.0;
    u.m[1] = -ma; u.re[1] = RS2;                     u.im[1] = 0.0;
  } else {
    int mm = -ma; u.n = 2;
    u.m[0] = -mm; u.re[0] = 0.0; u.im[0] = RS2;
    u.m[1] =  mm; u.re[1] = 0.0; u.im[1] = ((mm & 1) ? RS2 : -RS2);
  }
  return u;
}

constexpr double real_cg_entry(int l1, int a, int l2, int b, int l3, int c) {
  CURow u1 = cu_row(l1, a), u2 = cu_row(l2, b), u3 = cu_row(l3, c);
  double sre = 0.0, sim = 0.0;
  for (int x = 0; x < u1.n; ++x)
    for (int y = 0; y < u2.n; ++y)
      for (int z = 0; z < u3.n; ++z) {
        int m1 = u1.m[x], m2 = u2.m[y], m3 = u3.m[z];
        if (m1 + m2 != m3) continue;
        double cg = cg_complex(l1, m1, l2, m2, l3, m3);
        if (cg == 0.0) continue;
        double are = u1.re[x], aim = u1.im[x], bre = u2.re[y], bim = u2.im[y];
        double pre = are * bre - aim * bim, pim = are * bim + aim * bre;
        double cre = u3.re[z], cim = -u3.im[z];
        sre += (pre * cre - pim * cim) * cg;
        sim += (pre * cim + pim * cre) * cg;
      }
  return ((l1 + l2 + l3) & 1) ? sim : sre;
}

struct Y25D { double y[25]; };
constexpr Y25D csh25(double x, double y, double z) {
  Y25D Y{};
  double x2 = x * x, y2 = y * y, z2 = z * z;
  Y.y[0] = 0.28209479177387814;
  Y.y[1] = 0.4886025119029199 * y;
  Y.y[2] = 0.4886025119029199 * z;
  Y.y[3] = 0.4886025119029199 * x;
  Y.y[4] = 1.0925484305920792 * x * y;
  Y.y[5] = 1.0925484305920792 * y * z;
  Y.y[6] = 0.31539156525252005 * (3.0 * z2 - 1.0);
  Y.y[7] = 1.0925484305920792 * x * z;
  Y.y[8] = 0.5462742152960396 * (x2 - y2);
  Y.y[9] = 0.5900435899266435 * y * (3.0 * x2 - y2);
  Y.y[10] = 2.890611442640554 * x * y * z;
  Y.y[11] = 0.4570457994644658 * y * (5.0 * z2 - 1.0);
  Y.y[12] = 0.3731763325901154 * z * (5.0 * z2 - 3.0);
  Y.y[13] = 0.4570457994644658 * x * (5.0 * z2 - 1.0);
  Y.y[14] = 1.445305721320277 * z * (x2 - y2);
  Y.y[15] = 0.5900435899266435 * x * (x2 - 3.0 * y2);
  Y.y[16] = 2.5033429417967046 * x * y * (x2 - y2);
  Y.y[17] = 1.7701307697799304 * y * z * (3.0 * x2 - y2);
  Y.y[18] = 0.9461746957575601 * x * y * (7.0 * z2 - 1.0);
  Y.y[19] = 0.6690465435572892 * y * z * (7.0 * z2 - 3.0);
  Y.y[20] = 0.10578554691520431 * (35.0 * z2 * z2 - 30.0 * z2 + 3.0);
  Y.y[21] = 0.6690465435572892 * x * z * (7.0 * z2 - 3.0);
  Y.y[22] = 0.47308734787878004 * (x2 - y2) * (7.0 * z2 - 1.0);
  Y.y[23] = 1.7701307697799304 * x * z * (x2 - 3.0 * y2);
  Y.y[24] = 0.6258357354491761 * (x2 * x2 - 6.0 * x2 * y2 + y2 * y2);
  return Y;
}

constexpr double compute_A_even(int e) {
  int l1 = ETRI.l1[e], l2 = ETRI.l2[e], l3 = ETRI.l3[e];
  double ux = 0.437, uy = -0.602, uz = 0.668;
  double n = csqrt(ux * ux + uy * uy + uz * uz);
  Y25D Y = csh25(ux / n, uy / n, uz / n);
  int c0 = 2 * l3;
  double den = Y.y[l3 * l3 + c0];
  double num = 0.0;
  for (int a = 0; a < 2 * l1 + 1; ++a)
    for (int b = 0; b < 2 * l2 + 1; ++b) {
      double v = real_cg_entry(l1, a, l2, b, l3, c0);
      if (v != 0.0) num += v * Y.y[l1 * l1 + a] * Y.y[l2 * l2 + b];
    }
  return num / den;
}

template <int E> inline constexpr float A_of = (float)compute_A_even(E);
constexpr float AT42[42] = {
    A_of<0>,  A_of<1>,  A_of<2>,  A_of<3>,  A_of<4>,  A_of<5>,  A_of<6>,
    A_of<7>,  A_of<8>,  A_of<9>,  A_of<10>, A_of<11>, A_of<12>, A_of<13>,
    A_of<14>, A_of<15>, A_of<16>, A_of<17>, A_of<18>, A_of<19>, A_of<20>,
    A_of<21>, A_of<22>, A_of<23>, A_of<24>, A_of<25>, A_of<26>, A_of<27>,
    A_of<28>, A_of<29>, A_of<30>, A_of<31>, A_of<32>, A_of<33>, A_of<34>,
    A_of<35>, A_of<36>, A_of<37>, A_of<38>, A_of<39>, A_of<40>, A_of<41>};

// ===========================================================================
// Device helpers
// ===========================================================================
DEVINL unsigned short f2bf(float x) {  // RNE fp32 -> bf16
  unsigned u = __float_as_uint(x);
  u += 0x7FFFu + ((u >> 16) & 1u);
  return (unsigned short)(u >> 16);
}

DEVINL void sh25(float x, float y, float z, float* Y) {
  float x2 = x * x, y2 = y * y, z2 = z * z;
  Y[0] = 0.28209479177387814f;
  Y[1] = 0.4886025119029199f * y;
  Y[2] = 0.4886025119029199f * z;
  Y[3] = 0.4886025119029199f * x;
  Y[4] = 1.0925484305920792f * x * y;
  Y[5] = 1.0925484305920792f * y * z;
  Y[6] = 0.31539156525252005f * (3.0f * z2 - 1.0f);
  Y[7] = 1.0925484305920792f * x * z;
  Y[8] = 0.5462742152960396f * (x2 - y2);
  Y[9] = 0.5900435899266435f * y * (3.0f * x2 - y2);
  Y[10] = 2.890611442640554f * x * y * z;
  Y[11] = 0.4570457994644658f * y * (5.0f * z2 - 1.0f);
  Y[12] = 0.3731763325901154f * z * (5.0f * z2 - 3.0f);
  Y[13] = 0.4570457994644658f * x * (5.0f * z2 - 1.0f);
  Y[14] = 1.445305721320277f * z * (x2 - y2);
  Y[15] = 0.5900435899266435f * x * (x2 - 3.0f * y2);
  Y[16] = 2.5033429417967046f * x * y * (x2 - y2);
  Y[17] = 1.7701307697799304f * y * z * (3.0f * x2 - y2);
  Y[18] = 0.9461746957575601f * x * y * (7.0f * z2 - 1.0f);
  Y[19] = 0.6690465435572892f * y * z * (7.0f * z2 - 3.0f);
  Y[20] = 0.10578554691520431f * (35.0f * z2 * z2 - 30.0f * z2 + 3.0f);
  Y[21] = 0.6690465435572892f * x * z * (7.0f * z2 - 3.0f);
  Y[22] = 0.47308734787878004f * (x2 - y2) * (7.0f * z2 - 1.0f);
  Y[23] = 1.7701307697799304f * x * z * (x2 - 3.0f * y2);
  Y[24] = 0.6258357354491761f * (x2 * x2 - 6.0f * x2 * y2 + y2 * y2);
}

// ===========================================================================
// CSR build
// ===========================================================================
__global__ void khist(const int* __restrict__ nbr, int* __restrict__ counts, int P) {
  int p = blockIdx.x * 256 + threadIdx.x;
  if (p < P) atomicAdd(&counts[nbr[p]], 1);
}

__global__ void kscan(const int* __restrict__ counts, int* __restrict__ offsets,
                      int* __restrict__ cursor, int A, int P) {
  __shared__ int sh[256];
  int t = threadIdx.x;
  int items = A / 256;
  int local[16];
  int sum = 0;
  for (int u = 0; u < items; ++u) { local[u] = sum; sum += counts[t * items + u]; }
  sh[t] = sum;
  __syncthreads();
  for (int off = 1; off < 256; off <<= 1) {
    int v = (t >= off) ? sh[t - off] : 0;
    __syncthreads();
    sh[t] += v;
    __syncthreads();
  }
  int base = sh[t] - sum;
  for (int u = 0; u < items; ++u) {
    int o = base + local[u];
    offsets[t * items + u] = o;
    cursor[t * items + u] = o;
  }
  if (t == 255) offsets[A] = P;
}

__global__ void kscat(const int* __restrict__ nbr, int* __restrict__ cursor,
                      int* __restrict__ plist, int P) {
  int p = blockIdx.x * 256 + threadIdx.x;
  if (p < P) {
    int a = nbr[p];
    int pos = atomicAdd(&cursor[a], 1);
    plist[pos] = p;
  }
}

// ===========================================================================
// ktw: W1,W2 (fp32 [l][c][g]) -> WT (bf16 [l*64+g][c]) for MFMA B-fragments
// ===========================================================================
__global__ void ktw(const float* __restrict__ W1, const float* __restrict__ W2,
                    unsigned short* __restrict__ WT) {
  int idx = blockIdx.x * 256 + threadIdx.x;
  if (idx >= 40960) return;
  int c = idx & 63, g = (idx >> 6) & 63, l = idx >> 12;
  const float* W = (l < 5) ? (W1 + (size_t)l * 4096) : (W2 + (size_t)(l - 5) * 4096);
  WT[idx] = f2bf(W[c * 64 + g]);
}

// ===========================================================================
// k2G: MFMA GEMV (R[128x64] x W[64x640]) + triple contraction -> Gout.
// grid (P/128, 4): block handles 128 pairs x 16-g chunk. bf16 in, fp32 acc.
// ===========================================================================
__global__ __launch_bounds__(256) void k2G(const int* __restrict__ Z,
                                           const int* __restrict__ nbr,
                                           const float* __restrict__ disp,
                                           const float* __restrict__ se,
                                           const unsigned short* __restrict__ WT,
                                           const float* __restrict__ b1,
                                           const float* __restrict__ b2,
                                           float* __restrict__ Gout, int P) {
  __shared__ alignas(16) unsigned short rad[128 * 72];  // [pair][c], pad 64->72
  const int p0 = blockIdx.x * 128;
  const int g0 = blockIdx.y * 16;
  const int t = threadIdx.x;

  // ---- stage radial tile (2 threads per pair, 32 c each) ----
  {
    int pl = t >> 1, half = t & 1;
    int p = p0 + pl;
    int zj = Z[nbr[P + p]];
    float dx = disp[3 * p], dy = disp[3 * p + 1], dz = disp[3 * p + 2];
    float r = sqrtf(dx * dx + dy * dy + dz * dz + 1e-12f);
    float env = 0.5f * (__cosf(3.14159265358979f * fminf(r * 0.2f, 1.0f)) + 1.0f);
    const float delta = 5.0f / 63.0f;
    const float w = 0.5f / (delta * delta);
    int c0 = half * 32;
    const float4* s4 = (const float4*)(se + (size_t)zj * 64 + c0);
    unsigned* radw = (unsigned*)rad;
#pragma unroll
    for (int i = 0; i < 8; ++i) {
      float4 s = s4[i];
      float d0 = r - (float)(c0 + 4 * i + 0) * delta;
      float d1 = r - (float)(c0 + 4 * i + 1) * delta;
      float d2 = r - (float)(c0 + 4 * i + 2) * delta;
      float d3 = r - (float)(c0 + 4 * i + 3) * delta;
      float v0 = __expf(-w * d0 * d0) * env * s.x;
      float v1 = __expf(-w * d1 * d1) * env * s.y;
      float v2 = __expf(-w * d2 * d2) * env * s.z;
      float v3 = __expf(-w * d3 * d3) * env * s.w;
      radw[pl * 36 + half * 16 + 2 * i] =
          (unsigned)f2bf(v0) | ((unsigned)f2bf(v1) << 16);
      radw[pl * 36 + half * 16 + 2 * i + 1] =
          (unsigned)f2bf(v2) | ((unsigned)f2bf(v3) << 16);
    }
  }
  __syncthreads();

  const int lane = t & 63, wv = t >> 6;
  const int n = lane & 15, quad = lane >> 4;
  const int g = g0 + n;
  const float invY0 = 3.5449077018110318f;

  // ---- B-fragments: 10 l x 2 k-steps, straight from global WT (L2-hot) ----
  bf16x8 B[10][2];
#pragma unroll
  for (int l = 0; l < 10; ++l)
#pragma unroll
    for (int kk = 0; kk < 2; ++kk)
      B[l][kk] = *(const bf16x8*)(WT + (((size_t)l * 64 + g) * 64 + kk * 32 + quad * 8));

  float bb1 = b1[g] * invY0, bb2 = b2[g] * invY0;

  const int m0 = wv * 32;
#pragma unroll
  for (int mt = 0; mt < 2; ++mt) {
    int row = m0 + mt * 16 + n;
    bf16x8 A0 = *(const bf16x8*)(rad + row * 72 + quad * 8);
    bf16x8 A1 = *(const bf16x8*)(rad + row * 72 + 32 + quad * 8);
    f32x4 C[10];
#pragma unroll
    for (int l = 0; l < 10; ++l) C[l] = (f32x4){0.f, 0.f, 0.f, 0.f};
#pragma unroll
    for (int l = 0; l < 10; ++l) {
      C[l] = __builtin_amdgcn_mfma_f32_16x16x32_bf16(A0, B[l][0], C[l], 0, 0, 0);
      C[l] = __builtin_amdgcn_mfma_f32_16x16x32_bf16(A1, B[l][1], C[l], 0, 0, 0);
    }
#pragma unroll
    for (int r = 0; r < 4; ++r) { C[0][r] += bb1; C[5][r] += bb2; }

    // contraction: G[l3] += A(l1,l2,l3) * rv1[l1]*rv2[l2]  (register f32x4 math)
    f32x4 Gac[5];
#pragma unroll
    for (int l = 0; l < 5; ++l) Gac[l] = (f32x4){0.f, 0.f, 0.f, 0.f};
#pragma unroll
    for (int l1 = 0; l1 < 5; ++l1)
#pragma unroll
      for (int l2 = 0; l2 < 5; ++l2) {
        f32x4 pr = C[l1] * C[5 + l2];
#pragma unroll
        for (int e = 0; e < 42; ++e)
          if ((int)ETRI.l1[e] == l1 && (int)ETRI.l2[e] == l2)
            Gac[(int)ETRI.l3[e]] += AT42[e] * pr;
      }

    // store: C/D layout row = quad*4 + r, col = n
    int prow = p0 + m0 + mt * 16 + quad * 4;
#pragma unroll
    for (int l3 = 0; l3 < 5; ++l3)
#pragma unroll
      for (int r = 0; r < 4; ++r)
        Gout[(size_t)(prow + r) * 320 + l3 * 64 + g] = Gac[l3][r];
  }
}

// ===========================================================================
// k3: block per atom (4 waves), lane = f. Pairs strided across waves,
// LDS tree-reduce, fused emb epilogue.
// ===========================================================================
__global__ __launch_bounds__(256) void k3(const float* __restrict__ G,
                                          const float* __restrict__ disp,
                                          const int* __restrict__ Z,
                                          const float* __restrict__ se,
                                          const float* __restrict__ Wt,
                                          const float* __restrict__ bt,
                                          const int* __restrict__ offsets,
                                          const int* __restrict__ plist,
                                          float* __restrict__ out, int P) {
  __shared__ float red[3 * 1600];
  int atom = blockIdx.x;
  int f = threadIdx.x & 63, wv = threadIdx.x >> 6;
  float acc[25];
#pragma unroll
  for (int k = 0; k < 25; ++k) acc[k] = 0.f;
  int beg = offsets[atom], end = offsets[atom + 1];

  for (int q = beg + wv; q < end; q += 4) {
    int p = __builtin_amdgcn_readfirstlane(plist[q]);
    float dx = disp[3 * p], dy = disp[3 * p + 1], dz = disp[3 * p + 2];
    const float* Gp = G + (size_t)p * 320 + f;
    float g0 = Gp[0], g1 = Gp[64], g2 = Gp[128], g3 = Gp[192], g4 = Gp[256];
    float r = sqrtf(dx * dx + dy * dy + dz * dz + 1e-12f);
    float inv = 1.0f / r;
    float Y[25];
    sh25(dx * inv, dy * inv, dz * inv, Y);
    acc[0] = fmaf(Y[0], g0, acc[0]);
#pragma unroll
    for (int k = 1; k < 4; ++k)   acc[k] = fmaf(Y[k], g1, acc[k]);
#pragma unroll
    for (int k = 4; k < 9; ++k)   acc[k] = fmaf(Y[k], g2, acc[k]);
#pragma unroll
    for (int k = 9; k < 16; ++k)  acc[k] = fmaf(Y[k], g3, acc[k]);
#pragma unroll
    for (int k = 16; k < 25; ++k) acc[k] = fmaf(Y[k], g4, acc[k]);
  }

  if (wv > 0) {
#pragma unroll
    for (int k = 0; k < 25; ++k) red[(wv - 1) * 1600 + k * 64 + f] = acc[k];
  }
  __syncthreads();
  if (wv == 0) {
#pragma unroll
    for (int k = 0; k < 25; ++k)
      acc[k] += red[k * 64 + f] + red[1600 + k * 64 + f] + red[3200 + k * 64 + f];
    int z = Z[atom];
    float e = bt[f];
    for (int c = 0; c < 64; ++c)
      e = fmaf(se[(size_t)z * 64 + c], Wt[(size_t)c * 64 + f], e);
#pragma unroll
    for (int k = 0; k < 25; ++k)
      out[(size_t)atom * 1600 + (size_t)k * 64 + f] = fmaf(acc[k], e, (k == 0) ? e : 0.f);
  }
}

// ===========================================================================
// Launch
// ===========================================================================
static inline size_t align256(size_t x) { return (x + 255) & ~(size_t)255; }

extern "C" void kernel_launch(void* const* d_in, const int* in_sizes, int n_in,
                              void* d_out, int out_size, void* d_ws, size_t ws_size,
                              hipStream_t stream) {
  const int*   Z    = (const int*)d_in[0];
  const float* disp = (const float*)d_in[1];
  const int*   nbr  = (const int*)d_in[2];
  const float* se   = (const float*)d_in[3];
  const float* Wt   = (const float*)d_in[4];
  const float* bt   = (const float*)d_in[5];
  const float* W1   = (const float*)d_in[6];
  const float* b1   = (const float*)d_in[7];
  const float* W2   = (const float*)d_in[8];
  const float* b2   = (const float*)d_in[9];
  float* out = (float*)d_out;

  const int A = in_sizes[0];
  const int P = in_sizes[1] / 3;

  char* ws = (char*)d_ws;
  size_t o = 0;
  float*          G    = (float*)(ws + o);          o += align256((size_t)P * 320 * 4);
  unsigned short* WT   = (unsigned short*)(ws + o); o += align256((size_t)40960 * 2);
  int* counts  = (int*)(ws + o); o += align256((size_t)A * 4);
  int* offsets = (int*)(ws + o); o += align256((size_t)(A + 1) * 4);
  int* cursor  = (int*)(ws + o); o += align256((size_t)A * 4);
  int* plist   = (int*)(ws + o); o += align256((size_t)P * 4);
  (void)ws_size; (void)n_in; (void)out_size;

  int pb = (P + 255) / 256;

  hipMemsetAsync(counts, 0, (size_t)A * 4, stream);
  khist<<<pb, 256, 0, stream>>>(nbr, counts, P);
  kscan<<<1, 256, 0, stream>>>(counts, offsets, cursor, A, P);
  kscat<<<pb, 256, 0, stream>>>(nbr, cursor, plist, P);
  ktw<<<160, 256, 0, stream>>>(W1, W2, WT);
  dim3 g2((unsigned)(P / 128), 4, 1);
  k2G<<<g2, 256, 0, stream>>>(Z, nbr, disp, se, WT, b1, b2, G, P);
  k3<<<A, 256, 0, stream>>>(G, disp, Z, se, Wt, bt, offsets, plist, out, P);
}